// Round 1
// baseline (2496.241 us; speedup 1.0000x reference)
//
#include <hip/hip_runtime.h>
#include <hip/hip_bf16.h>

#define NT 8192      // tokens
#define HD 2048      // hidden
#define NE 8         // experts
// TOP_K = 2 hard-coded

// ---------------------------------------------------------------------------
// ws layout (d_ws is poisoned 0xAA before every launch -> we init everything):
//   +0     int   counts[8]
//   +32    int   offsets[8]
//   +64    int   cursors[8]
//   +256   int   tok_e[2*NT]        (per-token selected expert ids)
//   +256+64K   float tok_w[2*NT]    (per-token renormalized gate weights)
//   +256+128K  int   ids[2*NT]      (expert-compacted token ids)
//   +256+192K  float wts[2*NT]      (expert-compacted weights)
// total ~256 KiB
// ---------------------------------------------------------------------------

__global__ __launch_bounds__(256) void zero_out_kernel(float4* __restrict__ out,
                                                       int* __restrict__ counts) {
    size_t i = (size_t)blockIdx.x * 256 + threadIdx.x;
    out[i] = make_float4(0.f, 0.f, 0.f, 0.f);
    if (blockIdx.x == 0 && threadIdx.x < NE) counts[threadIdx.x] = 0;
}

// One wave (64 lanes) per token: logits = x[t] @ Wg + bg, top-2, renorm.
__global__ __launch_bounds__(256) void gating_kernel(
    const float* __restrict__ x, const float* __restrict__ Wg,
    const float* __restrict__ bg, int* __restrict__ counts,
    int* __restrict__ tok_e, float* __restrict__ tok_w)
{
    const int wave = threadIdx.x >> 6;
    const int lane = threadIdx.x & 63;
    const int t = (blockIdx.x << 2) + wave;
    const float* xr = x + (size_t)t * HD;

    float acc[NE];
    #pragma unroll
    for (int e = 0; e < NE; ++e) acc[e] = 0.f;

    for (int h = lane; h < HD; h += 64) {
        const float xv = xr[h];
        const float* wr = Wg + h * NE;   // Wg is [HD][NE] row-major
        #pragma unroll
        for (int e = 0; e < NE; ++e) acc[e] += xv * wr[e];
    }
    #pragma unroll
    for (int off = 32; off; off >>= 1) {
        #pragma unroll
        for (int e = 0; e < NE; ++e) acc[e] += __shfl_xor(acc[e], off);
    }

    if (lane == 0) {
        float l[NE];
        #pragma unroll
        for (int e = 0; e < NE; ++e) l[e] = acc[e] + bg[e];
        // top-2, lower index wins ties (jax.lax.top_k semantics)
        int i0 = 0, i1 = -1;
        float m0 = l[0], m1 = -__builtin_inff();
        #pragma unroll
        for (int e = 1; e < NE; ++e) {
            if (l[e] > m0)      { m1 = m0; i1 = i0; m0 = l[e]; i0 = e; }
            else if (l[e] > m1) { m1 = l[e]; i1 = e; }
        }
        // renormalized top-2 softmax weights; full softmax denom cancels
        const float ex = expf(m1 - m0);         // <= 1
        const float w0 = 1.f / (1.f + ex);
        const float w1 = ex  / (1.f + ex);
        tok_e[2 * t]     = i0;
        tok_e[2 * t + 1] = i1;
        tok_w[2 * t]     = w0;
        tok_w[2 * t + 1] = w1;
        atomicAdd(counts + i0, 1);
        atomicAdd(counts + i1, 1);
    }
}

__global__ void scan_kernel(const int* __restrict__ counts,
                            int* __restrict__ offsets, int* __restrict__ cursors) {
    if (threadIdx.x == 0) {
        int s = 0;
        for (int e = 0; e < NE; ++e) { offsets[e] = s; cursors[e] = s; s += counts[e]; }
    }
}

__global__ __launch_bounds__(256) void scatter_kernel(
    const int* __restrict__ tok_e, const float* __restrict__ tok_w,
    int* __restrict__ cursors, int* __restrict__ ids, float* __restrict__ wts)
{
    const int t = blockIdx.x * 256 + threadIdx.x;
    #pragma unroll
    for (int k = 0; k < 2; ++k) {
        const int e = tok_e[2 * t + k];
        const int p = atomicAdd(cursors + e, 1);
        ids[p] = t;
        wts[p] = tok_w[2 * t + k];
    }
}

// ---------------------------------------------------------------------------
// Per-expert gathered GEMM: out[t] += w * relu(x[t] @ We[e] + be[e])
// 64x64 output tile, BK=32, 256 threads, 4x4 register blocking (fp32 VALU).
// ---------------------------------------------------------------------------
#define BM 64
#define BN 64
#define BK 32

__global__ __launch_bounds__(256) void expert_gemm_kernel(
    const float* __restrict__ x, const float* __restrict__ We,
    const float* __restrict__ be, const int* __restrict__ offsets,
    const int* __restrict__ counts, const int* __restrict__ ids,
    const float* __restrict__ wts, float* __restrict__ out)
{
    const int e    = blockIdx.z;
    const int cnt  = counts[e];
    const int row0 = blockIdx.y * BM;
    if (row0 >= cnt) return;                 // static grid covers worst case
    const int base = offsets[e];
    const int m    = min(BM, cnt - row0);
    const int n0   = blockIdx.x * BN;

    __shared__ float xs[BK][BM + 1];         // +1 pad: A store is strided
    __shared__ float bs[BK][BN];
    __shared__ int   rtok[BM];
    __shared__ float rw[BM];

    const int tid = threadIdx.x;
    if (tid < BM) {
        const int r = tid < m ? tid : (m - 1);   // clamp padding rows to valid id
        rtok[tid] = ids[base + row0 + r];
        rw[tid]   = tid < m ? wts[base + row0 + tid] : 0.f;
    }
    __syncthreads();

    const float* Wb = We + (size_t)e * HD * HD;
    const int tx = tid & 15, ty = tid >> 4;

    float acc[4][4];
    #pragma unroll
    for (int i = 0; i < 4; ++i)
        #pragma unroll
        for (int j = 0; j < 4; ++j) acc[i][j] = 0.f;

    const int ak = tid & 31;                 // A loader: k within tile
    const int ar = tid >> 5;                 // A loader: row group (8 rows/pass)
    const int bn = tid & 63;                 // B loader: col
    const int bk = tid >> 6;                 // B loader: k group (4 k/pass)

    // hoist gathered row pointers
    const float* arow[8];
    #pragma unroll
    for (int p = 0; p < 8; ++p)
        arow[p] = x + (size_t)rtok[ar + p * 8] * HD + ak;

    for (int k0 = 0; k0 < HD; k0 += BK) {
        #pragma unroll
        for (int p = 0; p < 8; ++p)
            xs[ak][ar + p * 8] = arow[p][k0];
        #pragma unroll
        for (int p = 0; p < 8; ++p) {
            const int kk = bk + p * 4;
            bs[kk][bn] = Wb[(size_t)(k0 + kk) * HD + n0 + bn];
        }
        __syncthreads();
        #pragma unroll
        for (int kk = 0; kk < BK; ++kk) {
            float a[4], b[4];
            #pragma unroll
            for (int i = 0; i < 4; ++i) a[i] = xs[kk][ty * 4 + i];
            #pragma unroll
            for (int j = 0; j < 4; ++j) b[j] = bs[kk][tx * 4 + j];
            #pragma unroll
            for (int i = 0; i < 4; ++i)
                #pragma unroll
                for (int j = 0; j < 4; ++j) acc[i][j] += a[i] * b[j];
        }
        __syncthreads();
    }

    #pragma unroll
    for (int i = 0; i < 4; ++i) {
        const int r = ty * 4 + i;
        if (r < m) {
            const int   t = rtok[r];
            const float w = rw[r];
            #pragma unroll
            for (int j = 0; j < 4; ++j) {
                const int n = n0 + tx * 4 + j;
                float h = acc[i][j] + be[e * HD + n];
                h = fmaxf(h, 0.f) * w;
                atomicAdd(out + (size_t)t * HD + n, h);
            }
        }
    }
}

extern "C" void kernel_launch(void* const* d_in, const int* in_sizes, int n_in,
                              void* d_out, int out_size, void* d_ws, size_t ws_size,
                              hipStream_t stream) {
    const float* x  = (const float*)d_in[0];
    const float* Wg = (const float*)d_in[1];
    const float* bg = (const float*)d_in[2];
    const float* We = (const float*)d_in[3];
    const float* be = (const float*)d_in[4];
    float* out = (float*)d_out;

    char* ws = (char*)d_ws;
    int*   counts  = (int*)(ws);
    int*   offsets = (int*)(ws + 32);
    int*   cursors = (int*)(ws + 64);
    int*   tok_e   = (int*)(ws + 256);
    float* tok_w   = (float*)(ws + 256 + 64 * 1024);
    int*   ids     = (int*)(ws + 256 + 128 * 1024);
    float* wts     = (float*)(ws + 256 + 192 * 1024);

    zero_out_kernel<<<(NT * HD / 4) / 256, 256, 0, stream>>>((float4*)out, counts);
    gating_kernel<<<NT / 4, 256, 0, stream>>>(x, Wg, bg, counts, tok_e, tok_w);
    scan_kernel<<<1, 64, 0, stream>>>(counts, offsets, cursors);
    scatter_kernel<<<NT / 256, 256, 0, stream>>>(tok_e, tok_w, cursors, ids, wts);

    dim3 grid(HD / BN, NT / BM, NE);   // worst case: all tokens on one expert
    expert_gemm_kernel<<<grid, 256, 0, stream>>>(x, We, be, offsets, counts, ids, wts, out);
}

// Round 8
// 931.813 us; speedup vs baseline: 2.6789x; 2.6789x over previous
//
#include <hip/hip_runtime.h>
#include <hip/hip_bf16.h>

#define NT 8192      // tokens
#define HD 2048      // hidden
#define NE 8         // experts
// TOP_K = 2 hard-coded

typedef unsigned short u16;
typedef u16   u16x8 __attribute__((ext_vector_type(8)));
typedef short s16x8 __attribute__((ext_vector_type(8)));   // MFMA bf16 frag (4 VGPRs)
typedef float f32x4 __attribute__((ext_vector_type(4)));   // MFMA acc

__device__ __forceinline__ u16 f2bf(float f) {             // fp32 -> bf16 RTNE
    unsigned u = __float_as_uint(f);
    u += 0x7fffu + ((u >> 16) & 1u);
    return (u16)(u >> 16);
}

// ---------------------------------------------------------------------------
// ws layout: counts/offsets/cursors + token routing arrays (~256 KiB)
// ---------------------------------------------------------------------------

__global__ __launch_bounds__(256) void zero_out_kernel(float4* __restrict__ out,
                                                       int* __restrict__ counts) {
    size_t i = (size_t)blockIdx.x * 256 + threadIdx.x;
    out[i] = make_float4(0.f, 0.f, 0.f, 0.f);
    if (blockIdx.x == 0 && threadIdx.x < NE) counts[threadIdx.x] = 0;
}

__global__ __launch_bounds__(256) void gating_kernel(
    const float* __restrict__ x, const float* __restrict__ Wg,
    const float* __restrict__ bg, int* __restrict__ counts,
    int* __restrict__ tok_e, float* __restrict__ tok_w)
{
    const int wave = threadIdx.x >> 6;
    const int lane = threadIdx.x & 63;
    const int t = (blockIdx.x << 2) + wave;
    const float* xr = x + (size_t)t * HD;

    float acc[NE];
    #pragma unroll
    for (int e = 0; e < NE; ++e) acc[e] = 0.f;

    for (int h = lane; h < HD; h += 64) {
        const float xv = xr[h];
        const float* wr = Wg + h * NE;
        #pragma unroll
        for (int e = 0; e < NE; ++e) acc[e] += xv * wr[e];
    }
    #pragma unroll
    for (int off = 32; off; off >>= 1) {
        #pragma unroll
        for (int e = 0; e < NE; ++e) acc[e] += __shfl_xor(acc[e], off);
    }

    if (lane == 0) {
        float l[NE];
        #pragma unroll
        for (int e = 0; e < NE; ++e) l[e] = acc[e] + bg[e];
        int i0 = 0, i1 = -1;
        float m0 = l[0], m1 = -__builtin_inff();
        #pragma unroll
        for (int e = 1; e < NE; ++e) {
            if (l[e] > m0)      { m1 = m0; i1 = i0; m0 = l[e]; i0 = e; }
            else if (l[e] > m1) { m1 = l[e]; i1 = e; }
        }
        const float ex = expf(m1 - m0);
        const float w0 = 1.f / (1.f + ex);
        const float w1 = ex  / (1.f + ex);
        tok_e[2 * t]     = i0;
        tok_e[2 * t + 1] = i1;
        tok_w[2 * t]     = w0;
        tok_w[2 * t + 1] = w1;
        atomicAdd(counts + i0, 1);
        atomicAdd(counts + i1, 1);
    }
}

__global__ void scan_kernel(const int* __restrict__ counts,
                            int* __restrict__ offsets, int* __restrict__ cursors) {
    if (threadIdx.x == 0) {
        int s = 0;
        for (int e = 0; e < NE; ++e) { offsets[e] = s; cursors[e] = s; s += counts[e]; }
    }
}

__global__ __launch_bounds__(256) void scatter_kernel(
    const int* __restrict__ tok_e, const float* __restrict__ tok_w,
    int* __restrict__ cursors, int* __restrict__ ids, float* __restrict__ wts)
{
    const int t = blockIdx.x * 256 + threadIdx.x;
    #pragma unroll
    for (int k = 0; k < 2; ++k) {
        const int e = tok_e[2 * t + k];
        const int p = atomicAdd(cursors + e, 1);
        ids[p] = t;
        wts[p] = tok_w[2 * t + k];
    }
}

// ---------------------------------------------------------------------------
// bf16-MFMA gathered expert GEMM: out[t] += w * relu(x[t] @ We[e] + be[e])
// 128x128x32 tile, 256 threads = 4 waves, each wave a 64x64 quadrant
// (4x4 frags of mfma_f32_16x16x32_bf16). fp32->bf16 convert in-flight.
// W columns gathered at GLOBAL load (coalesced float2 across lanes) so both
// LDS tiles are [row][k] with 8-consecutive-k per lane -> ds_read_b128 frags.
// LDW=40 pad: 80 B row stride -> only 2-way bank aliasing (free), 16B aligned.
// ---------------------------------------------------------------------------
#define BM 128
#define BN 128
#define BK 32
#define LDW 40

__global__ __launch_bounds__(256) void expert_gemm_kernel(
    const float* __restrict__ x, const float* __restrict__ We,
    const float* __restrict__ be, const int* __restrict__ offsets,
    const int* __restrict__ counts, const int* __restrict__ ids,
    const float* __restrict__ wts, float* __restrict__ out)
{
    const int e    = blockIdx.z;
    const int cnt  = counts[e];
    const int row0 = blockIdx.y * BM;
    if (row0 >= cnt) return;                 // static grid covers worst case
    const int base = offsets[e];
    const int m    = min(BM, cnt - row0);
    const int n0   = blockIdx.x * BN;

    __shared__ u16   as[BM][LDW];
    __shared__ u16   bs[BN][LDW];
    __shared__ int   rtok[BM];
    __shared__ float rw[BM];

    const int tid = threadIdx.x;
    if (tid < BM) {
        const int r = tid < m ? tid : (m - 1);   // clamp pad rows to a valid id
        rtok[tid] = ids[base + row0 + r];
        rw[tid]   = tid < m ? wts[base + row0 + tid] : 0.f;
    }
    __syncthreads();

    // A staging role: each thread loads 16 consecutive k of one gathered row
    const int arow_i = tid >> 1;
    const int akh    = tid & 1;
    const float* arow = x + (size_t)rtok[arow_i] * HD + akh * 16;

    // B staging role: each thread gathers 8 k of a column-PAIR of W
    // (lane-adjacent float2 loads are contiguous 512B across a wave)
    const int bpr = tid & 63;                // n pair index
    const int bkg = tid >> 6;                // k group of 8
    const float* bcol = We + (size_t)e * HD * HD + (size_t)bkg * 8 * HD + n0 + 2 * bpr;

    const int lane = tid & 63;
    const int wid  = tid >> 6;
    const int wm   = (wid & 1) * 64;
    const int wn   = (wid >> 1) * 64;
    const int fr   = lane & 15;              // frag row/col
    const int fq   = lane >> 4;              // k-quad

    f32x4 acc[4][4] = {};

    for (int k0 = 0; k0 < HD; k0 += BK) {
        // issue global loads first (overlap previous MFMA phase)
        const float4 av0 = *(const float4*)(arow + k0);
        const float4 av1 = *(const float4*)(arow + k0 + 4);
        const float4 av2 = *(const float4*)(arow + k0 + 8);
        const float4 av3 = *(const float4*)(arow + k0 + 12);
        float2 bv[8];
        #pragma unroll
        for (int j = 0; j < 8; ++j)
            bv[j] = *(const float2*)(bcol + (size_t)(k0 + j) * HD);

        __syncthreads();                     // prior iter's frag reads done

        const u16x8 aw0 = { f2bf(av0.x), f2bf(av0.y), f2bf(av0.z), f2bf(av0.w),
                            f2bf(av1.x), f2bf(av1.y), f2bf(av1.z), f2bf(av1.w) };
        const u16x8 aw1 = { f2bf(av2.x), f2bf(av2.y), f2bf(av2.z), f2bf(av2.w),
                            f2bf(av3.x), f2bf(av3.y), f2bf(av3.z), f2bf(av3.w) };
        *(u16x8*)&as[arow_i][akh * 16]     = aw0;
        *(u16x8*)&as[arow_i][akh * 16 + 8] = aw1;

        const u16x8 bw0 = { f2bf(bv[0].x), f2bf(bv[1].x), f2bf(bv[2].x), f2bf(bv[3].x),
                            f2bf(bv[4].x), f2bf(bv[5].x), f2bf(bv[6].x), f2bf(bv[7].x) };
        const u16x8 bw1 = { f2bf(bv[0].y), f2bf(bv[1].y), f2bf(bv[2].y), f2bf(bv[3].y),
                            f2bf(bv[4].y), f2bf(bv[5].y), f2bf(bv[6].y), f2bf(bv[7].y) };
        *(u16x8*)&bs[2 * bpr][bkg * 8]     = bw0;
        *(u16x8*)&bs[2 * bpr + 1][bkg * 8] = bw1;

        __syncthreads();

        s16x8 af[4], bfrag[4];
        #pragma unroll
        for (int f = 0; f < 4; ++f) {
            af[f]    = *(const s16x8*)&as[wm + f * 16 + fr][fq * 8];
            bfrag[f] = *(const s16x8*)&bs[wn + f * 16 + fr][fq * 8];
        }
        #pragma unroll
        for (int mf = 0; mf < 4; ++mf)
            #pragma unroll
            for (int nf = 0; nf < 4; ++nf)
                acc[mf][nf] = __builtin_amdgcn_mfma_f32_16x16x32_bf16(
                    af[mf], bfrag[nf], acc[mf][nf], 0, 0, 0);
    }

    // epilogue: C/D layout col = lane&15, row = (lane>>4)*4 + reg  (m89/m91)
    #pragma unroll
    for (int nf = 0; nf < 4; ++nf) {
        const int   n    = n0 + wn + nf * 16 + fr;
        const float bias = be[e * HD + n];
        #pragma unroll
        for (int mf = 0; mf < 4; ++mf) {
            #pragma unroll
            for (int r = 0; r < 4; ++r) {
                const int row = wm + mf * 16 + fq * 4 + r;
                if (row < m) {
                    float h = acc[mf][nf][r] + bias;
                    h = fmaxf(h, 0.f) * rw[row];
                    atomicAdd(out + (size_t)rtok[row] * HD + n, h);
                }
            }
        }
    }
}

extern "C" void kernel_launch(void* const* d_in, const int* in_sizes, int n_in,
                              void* d_out, int out_size, void* d_ws, size_t ws_size,
                              hipStream_t stream) {
    const float* x  = (const float*)d_in[0];
    const float* Wg = (const float*)d_in[1];
    const float* bg = (const float*)d_in[2];
    const float* We = (const float*)d_in[3];
    const float* be = (const float*)d_in[4];
    float* out = (float*)d_out;

    char* ws = (char*)d_ws;
    int*   counts  = (int*)(ws);
    int*   offsets = (int*)(ws + 32);
    int*   cursors = (int*)(ws + 64);
    int*   tok_e   = (int*)(ws + 256);
    float* tok_w   = (float*)(ws + 256 + 64 * 1024);
    int*   ids     = (int*)(ws + 256 + 128 * 1024);
    float* wts     = (float*)(ws + 256 + 192 * 1024);

    zero_out_kernel<<<(NT * HD / 4) / 256, 256, 0, stream>>>((float4*)out, counts);
    gating_kernel<<<NT / 4, 256, 0, stream>>>(x, Wg, bg, counts, tok_e, tok_w);
    scan_kernel<<<1, 64, 0, stream>>>(counts, offsets, cursors);
    scatter_kernel<<<NT / 256, 256, 0, stream>>>(tok_e, tok_w, cursors, ids, wts);

    dim3 grid(HD / BN, NT / BM, NE);   // worst case: all tokens on one expert
    expert_gemm_kernel<<<grid, 256, 0, stream>>>(x, We, be, offsets, counts, ids, wts, out);
}

// Round 10
// 876.963 us; speedup vs baseline: 2.8465x; 1.0625x over previous
//
#include <hip/hip_runtime.h>
#include <hip/hip_bf16.h>

#define NT 8192      // tokens
#define HD 2048      // hidden
#define NE 8         // experts
// TOP_K = 2 hard-coded

typedef unsigned short u16;
typedef u16   u16x4 __attribute__((ext_vector_type(4)));
typedef u16   u16x8 __attribute__((ext_vector_type(8)));
typedef short s16x8 __attribute__((ext_vector_type(8)));   // MFMA bf16 frag (4 VGPRs)
typedef float f32x4 __attribute__((ext_vector_type(4)));   // MFMA acc

__device__ __forceinline__ u16 f2bf(float f) {             // fp32 -> bf16 RTNE
    unsigned u = __float_as_uint(f);
    u += 0x7fffu + ((u >> 16) & 1u);
    return (u16)(u >> 16);
}

// ---------------------------------------------------------------------------
// ws layout:
//   [0, 512KB)            routing: counts/offsets/cursors/tok_e/tok_w/ids/wts
//   [512KB, +32MB)        x_bf16   [NT][HD]
//   [512KB+32MB, +64MB)   WeT_bf16 [NE][HD(n)][HD(k)]  (transposed!)
// REQUIRED = 512KB + 96MB. If ws_size smaller -> fallback fp32-load path.
// ---------------------------------------------------------------------------
#define WS_XB   (1u << 19)
#define WS_WET  ((1u << 19) + (32u << 20))
#define WS_REQ  ((size_t)(1u << 19) + (96u << 20))

__global__ __launch_bounds__(256) void zero_out_kernel(float4* __restrict__ out,
                                                       int* __restrict__ counts) {
    size_t i = (size_t)blockIdx.x * 256 + threadIdx.x;
    out[i] = make_float4(0.f, 0.f, 0.f, 0.f);
    if (blockIdx.x == 0 && threadIdx.x < NE) counts[threadIdx.x] = 0;
}

// x fp32 -> bf16, 8 elems/thread
__global__ __launch_bounds__(256) void convert_x_kernel(const float* __restrict__ x,
                                                        u16* __restrict__ xb) {
    size_t i = ((size_t)blockIdx.x * 256 + threadIdx.x) * 8;
    const float4 a = *(const float4*)(x + i);
    const float4 b = *(const float4*)(x + i + 4);
    u16x8 v = { f2bf(a.x), f2bf(a.y), f2bf(a.z), f2bf(a.w),
                f2bf(b.x), f2bf(b.y), f2bf(b.z), f2bf(b.w) };
    *(u16x8*)(xb + i) = v;
}

// We[e][k][n] fp32 -> WeT[e][n][k] bf16, 32x32 LDS-tiled transpose
__global__ __launch_bounds__(256) void convert_we_kernel(const float* __restrict__ We,
                                                         u16* __restrict__ WeT) {
    const int e = blockIdx.z, k0 = blockIdx.y * 32, n0 = blockIdx.x * 32;
    __shared__ u16 tile[32][33];
    const float* src = We + (size_t)e * HD * HD;
    const int kl = threadIdx.x >> 5, nl = threadIdx.x & 31;
    #pragma unroll
    for (int i = 0; i < 4; ++i)
        tile[kl + i * 8][nl] = f2bf(src[(size_t)(k0 + kl + i * 8) * HD + n0 + nl]);
    __syncthreads();
    const int nr = threadIdx.x >> 3, kc = (threadIdx.x & 7) * 4;
    u16x4 v = { tile[kc][nr], tile[kc + 1][nr], tile[kc + 2][nr], tile[kc + 3][nr] };
    *(u16x4*)(WeT + (size_t)e * HD * HD + (size_t)(n0 + nr) * HD + k0 + kc) = v;
}

__global__ __launch_bounds__(256) void gating_kernel(
    const float* __restrict__ x, const float* __restrict__ Wg,
    const float* __restrict__ bg, int* __restrict__ counts,
    int* __restrict__ tok_e, float* __restrict__ tok_w)
{
    const int wave = threadIdx.x >> 6;
    const int lane = threadIdx.x & 63;
    const int t = (blockIdx.x << 2) + wave;
    const float* xr = x + (size_t)t * HD;

    float acc[NE];
    #pragma unroll
    for (int e = 0; e < NE; ++e) acc[e] = 0.f;

    for (int h = lane; h < HD; h += 64) {
        const float xv = xr[h];
        const float* wr = Wg + h * NE;
        #pragma unroll
        for (int e = 0; e < NE; ++e) acc[e] += xv * wr[e];
    }
    #pragma unroll
    for (int off = 32; off; off >>= 1) {
        #pragma unroll
        for (int e = 0; e < NE; ++e) acc[e] += __shfl_xor(acc[e], off);
    }

    if (lane == 0) {
        float l[NE];
        #pragma unroll
        for (int e = 0; e < NE; ++e) l[e] = acc[e] + bg[e];
        int i0 = 0, i1 = -1;
        float m0 = l[0], m1 = -__builtin_inff();
        #pragma unroll
        for (int e = 1; e < NE; ++e) {
            if (l[e] > m0)      { m1 = m0; i1 = i0; m0 = l[e]; i0 = e; }
            else if (l[e] > m1) { m1 = l[e]; i1 = e; }
        }
        const float ex = expf(m1 - m0);
        const float w0 = 1.f / (1.f + ex);
        const float w1 = ex  / (1.f + ex);
        tok_e[2 * t]     = i0;
        tok_e[2 * t + 1] = i1;
        tok_w[2 * t]     = w0;
        tok_w[2 * t + 1] = w1;
        atomicAdd(counts + i0, 1);
        atomicAdd(counts + i1, 1);
    }
}

__global__ void scan_kernel(const int* __restrict__ counts,
                            int* __restrict__ offsets, int* __restrict__ cursors) {
    if (threadIdx.x == 0) {
        int s = 0;
        for (int e = 0; e < NE; ++e) { offsets[e] = s; cursors[e] = s; s += counts[e]; }
    }
}

__global__ __launch_bounds__(256) void scatter_kernel(
    const int* __restrict__ tok_e, const float* __restrict__ tok_w,
    int* __restrict__ cursors, int* __restrict__ ids, float* __restrict__ wts)
{
    const int t = blockIdx.x * 256 + threadIdx.x;
    #pragma unroll
    for (int k = 0; k < 2; ++k) {
        const int e = tok_e[2 * t + k];
        const int p = atomicAdd(cursors + e, 1);
        ids[p] = t;
        wts[p] = tok_w[2 * t + k];
    }
}

#define BM 128
#define BN 128
#define BK 32
#define LDW 40

// ---------------------------------------------------------------------------
// Main path: both operands pre-converted bf16; We pre-transposed [e][n][k].
// Staging = pure short8 coalesced loads -> b128 LDS writes (row-per-thread-
// pair: ~even bank spread). No f2bf in the K-loop -> VALU freed for MFMA.
// ---------------------------------------------------------------------------
__global__ __launch_bounds__(256) void expert_gemm_bf16(
    const u16* __restrict__ xb, const u16* __restrict__ WeT,
    const float* __restrict__ be, const int* __restrict__ offsets,
    const int* __restrict__ counts, const int* __restrict__ ids,
    const float* __restrict__ wts, float* __restrict__ out)
{
    const int e    = blockIdx.z;
    const int cnt  = counts[e];
    const int row0 = blockIdx.y * BM;
    if (row0 >= cnt) return;
    const int base = offsets[e];
    const int m    = min(BM, cnt - row0);
    const int n0   = blockIdx.x * BN;

    __shared__ u16   as_[BM][LDW];
    __shared__ u16   bs[BN][LDW];
    __shared__ int   rtok[BM];
    __shared__ float rw[BM];

    const int tid = threadIdx.x;
    if (tid < BM) {
        const int r = tid < m ? tid : (m - 1);
        rtok[tid] = ids[base + row0 + r];
        rw[tid]   = tid < m ? wts[base + row0 + tid] : 0.f;
    }
    __syncthreads();

    const int hr = tid >> 1;              // row (A) / col (B) index 0..127
    const int kh = (tid & 1) * 16;        // k offset within BK
    const u16* arow = xb + (size_t)rtok[hr] * HD + kh;
    const u16* brow = WeT + (size_t)e * HD * HD + (size_t)(n0 + hr) * HD + kh;

    const int lane = tid & 63;
    const int wid  = tid >> 6;
    const int wm   = (wid & 1) * 64;
    const int wn   = (wid >> 1) * 64;
    const int fr   = lane & 15;
    const int fq   = lane >> 4;

    f32x4 acc[4][4] = {};

    for (int k0 = 0; k0 < HD; k0 += BK) {
        const u16x8 a0 = *(const u16x8*)(arow + k0);
        const u16x8 a1 = *(const u16x8*)(arow + k0 + 8);
        const u16x8 b0 = *(const u16x8*)(brow + k0);
        const u16x8 b1 = *(const u16x8*)(brow + k0 + 8);

        __syncthreads();                  // prior iter's frag reads done

        *(u16x8*)&as_[hr][kh]     = a0;
        *(u16x8*)&as_[hr][kh + 8] = a1;
        *(u16x8*)&bs[hr][kh]      = b0;
        *(u16x8*)&bs[hr][kh + 8]  = b1;

        __syncthreads();

        s16x8 af[4], bfrag[4];
        #pragma unroll
        for (int f = 0; f < 4; ++f) {
            af[f]    = *(const s16x8*)&as_[wm + f * 16 + fr][fq * 8];
            bfrag[f] = *(const s16x8*)&bs[wn + f * 16 + fr][fq * 8];
        }
        #pragma unroll
        for (int mf = 0; mf < 4; ++mf)
            #pragma unroll
            for (int nf = 0; nf < 4; ++nf)
                acc[mf][nf] = __builtin_amdgcn_mfma_f32_16x16x32_bf16(
                    af[mf], bfrag[nf], acc[mf][nf], 0, 0, 0);
    }

    #pragma unroll
    for (int nf = 0; nf < 4; ++nf) {
        const int   n    = n0 + wn + nf * 16 + fr;
        const float bias = be[e * HD + n];
        #pragma unroll
        for (int mf = 0; mf < 4; ++mf) {
            #pragma unroll
            for (int r = 0; r < 4; ++r) {
                const int row = wm + mf * 16 + fq * 4 + r;
                if (row < m) {
                    float h = acc[mf][nf][r] + bias;
                    h = fmaxf(h, 0.f) * rw[row];
                    atomicAdd(out + (size_t)rtok[row] * HD + n, h);
                }
            }
        }
    }
}

// ---------------------------------------------------------------------------
// Fallback (ws too small for staging buffers): round-8 validated kernel.
// ---------------------------------------------------------------------------
__global__ __launch_bounds__(256) void expert_gemm_fb(
    const float* __restrict__ x, const float* __restrict__ We,
    const float* __restrict__ be, const int* __restrict__ offsets,
    const int* __restrict__ counts, const int* __restrict__ ids,
    const float* __restrict__ wts, float* __restrict__ out)
{
    const int e    = blockIdx.z;
    const int cnt  = counts[e];
    const int row0 = blockIdx.y * BM;
    if (row0 >= cnt) return;
    const int base = offsets[e];
    const int m    = min(BM, cnt - row0);
    const int n0   = blockIdx.x * BN;

    __shared__ u16   as_[BM][LDW];
    __shared__ u16   bs[BN][LDW];
    __shared__ int   rtok[BM];
    __shared__ float rw[BM];

    const int tid = threadIdx.x;
    if (tid < BM) {
        const int r = tid < m ? tid : (m - 1);
        rtok[tid] = ids[base + row0 + r];
        rw[tid]   = tid < m ? wts[base + row0 + tid] : 0.f;
    }
    __syncthreads();

    const int arow_i = tid >> 1;
    const int akh    = tid & 1;
    const float* arow = x + (size_t)rtok[arow_i] * HD + akh * 16;
    const int bpr = tid & 63;
    const int bkg = tid >> 6;
    const float* bcol = We + (size_t)e * HD * HD + (size_t)bkg * 8 * HD + n0 + 2 * bpr;

    const int lane = tid & 63;
    const int wid  = tid >> 6;
    const int wm   = (wid & 1) * 64;
    const int wn   = (wid >> 1) * 64;
    const int fr   = lane & 15;
    const int fq   = lane >> 4;

    f32x4 acc[4][4] = {};

    for (int k0 = 0; k0 < HD; k0 += BK) {
        const float4 av0 = *(const float4*)(arow + k0);
        const float4 av1 = *(const float4*)(arow + k0 + 4);
        const float4 av2 = *(const float4*)(arow + k0 + 8);
        const float4 av3 = *(const float4*)(arow + k0 + 12);
        float2 bv[8];
        #pragma unroll
        for (int j = 0; j < 8; ++j)
            bv[j] = *(const float2*)(bcol + (size_t)(k0 + j) * HD);

        __syncthreads();

        const u16x8 aw0 = { f2bf(av0.x), f2bf(av0.y), f2bf(av0.z), f2bf(av0.w),
                            f2bf(av1.x), f2bf(av1.y), f2bf(av1.z), f2bf(av1.w) };
        const u16x8 aw1 = { f2bf(av2.x), f2bf(av2.y), f2bf(av2.z), f2bf(av2.w),
                            f2bf(av3.x), f2bf(av3.y), f2bf(av3.z), f2bf(av3.w) };
        *(u16x8*)&as_[arow_i][akh * 16]     = aw0;
        *(u16x8*)&as_[arow_i][akh * 16 + 8] = aw1;
        const u16x8 bw0 = { f2bf(bv[0].x), f2bf(bv[1].x), f2bf(bv[2].x), f2bf(bv[3].x),
                            f2bf(bv[4].x), f2bf(bv[5].x), f2bf(bv[6].x), f2bf(bv[7].x) };
        const u16x8 bw1 = { f2bf(bv[0].y), f2bf(bv[1].y), f2bf(bv[2].y), f2bf(bv[3].y),
                            f2bf(bv[4].y), f2bf(bv[5].y), f2bf(bv[6].y), f2bf(bv[7].y) };
        *(u16x8*)&bs[2 * bpr][bkg * 8]     = bw0;
        *(u16x8*)&bs[2 * bpr + 1][bkg * 8] = bw1;

        __syncthreads();

        s16x8 af[4], bfrag[4];
        #pragma unroll
        for (int f = 0; f < 4; ++f) {
            af[f]    = *(const s16x8*)&as_[wm + f * 16 + fr][fq * 8];
            bfrag[f] = *(const s16x8*)&bs[wn + f * 16 + fr][fq * 8];
        }
        #pragma unroll
        for (int mf = 0; mf < 4; ++mf)
            #pragma unroll
            for (int nf = 0; nf < 4; ++nf)
                acc[mf][nf] = __builtin_amdgcn_mfma_f32_16x16x32_bf16(
                    af[mf], bfrag[nf], acc[mf][nf], 0, 0, 0);
    }

    #pragma unroll
    for (int nf = 0; nf < 4; ++nf) {
        const int   n    = n0 + wn + nf * 16 + fr;
        const float bias = be[e * HD + n];
        #pragma unroll
        for (int mf = 0; mf < 4; ++mf) {
            #pragma unroll
            for (int r = 0; r < 4; ++r) {
                const int row = wm + mf * 16 + fq * 4 + r;
                if (row < m) {
                    float h = acc[mf][nf][r] + bias;
                    h = fmaxf(h, 0.f) * rw[row];
                    atomicAdd(out + (size_t)rtok[row] * HD + n, h);
                }
            }
        }
    }
}

extern "C" void kernel_launch(void* const* d_in, const int* in_sizes, int n_in,
                              void* d_out, int out_size, void* d_ws, size_t ws_size,
                              hipStream_t stream) {
    const float* x  = (const float*)d_in[0];
    const float* Wg = (const float*)d_in[1];
    const float* bg = (const float*)d_in[2];
    const float* We = (const float*)d_in[3];
    const float* be = (const float*)d_in[4];
    float* out = (float*)d_out;

    char* ws = (char*)d_ws;
    int*   counts  = (int*)(ws);
    int*   offsets = (int*)(ws + 32);
    int*   cursors = (int*)(ws + 64);
    int*   tok_e   = (int*)(ws + 256);
    float* tok_w   = (float*)(ws + 256 + 64 * 1024);
    int*   ids     = (int*)(ws + 256 + 128 * 1024);
    float* wts     = (float*)(ws + 256 + 192 * 1024);

    zero_out_kernel<<<(NT * HD / 4) / 256, 256, 0, stream>>>((float4*)out, counts);
    gating_kernel<<<NT / 4, 256, 0, stream>>>(x, Wg, bg, counts, tok_e, tok_w);
    scan_kernel<<<1, 64, 0, stream>>>(counts, offsets, cursors);
    scatter_kernel<<<NT / 256, 256, 0, stream>>>(tok_e, tok_w, cursors, ids, wts);

    dim3 grid(HD / BN, NT / BM, NE);   // worst case: all tokens on one expert

    if (ws_size >= WS_REQ) {
        u16* xb  = (u16*)(ws + WS_XB);
        u16* WeT = (u16*)(ws + WS_WET);
        convert_x_kernel<<<NT * HD / 8 / 256, 256, 0, stream>>>(x, xb);
        convert_we_kernel<<<dim3(HD / 32, HD / 32, NE), 256, 0, stream>>>(We, WeT);
        expert_gemm_bf16<<<grid, 256, 0, stream>>>(xb, WeT, be, offsets, counts, ids, wts, out);
    } else {
        expert_gemm_fb<<<grid, 256, 0, stream>>>(x, We, be, offsets, counts, ids, wts, out);
    }
}